// Round 7
// baseline (210.933 us; speedup 1.0000x reference)
//
#include <hip/hip_runtime.h>
#include <hip/hip_bf16.h>

typedef __attribute__((ext_vector_type(8))) short short8;
typedef __attribute__((ext_vector_type(4))) float floatx4;

#define MFMA16(a, b, c) __builtin_amdgcn_mfma_f32_16x16x32_bf16((a), (b), (c), 0, 0, 0)
#define GLOBAL_AS __attribute__((address_space(1)))
#define LDS_AS __attribute__((address_space(3)))

__device__ __forceinline__ unsigned short f2bf(float x) {
  union { float f; unsigned u; } v; v.f = x;
  unsigned r = v.u + 0x7FFFu + ((v.u >> 16) & 1u);  // RNE
  return (unsigned short)(r >> 16);
}

__device__ __forceinline__ short8 ld8(const unsigned short* p) {
  return *reinterpret_cast<const short8*>(p);
}

__device__ __forceinline__ void async_cp16(const unsigned short* g, unsigned short* l) {
  __builtin_amdgcn_global_load_lds((const GLOBAL_AS void*)g, (LDS_AS void*)l, 16, 0, 0);
}

// LPT-descending chunk order. chunk c<16: full q-tile j=c (j+1 passes).
// c>=16: s=c-16, j=16+(s>>1), half hf=s&1 of a split pair (8..16 passes).
__constant__ int ORD48[48] = {
    15, 44, 46, 47,  14, 40, 42, 43, 45,  13, 36, 38, 39, 41,
    12, 32, 34, 35, 37,  11, 28, 30, 31, 33,  10, 24, 26, 27, 29,
    9, 20, 22, 23, 25,  8, 16, 18, 19, 21,  7, 17,  6, 5, 4, 3, 2, 1, 0};

// ---------------- fused prep: x convert + both weight transposes ----------------
__global__ __launch_bounds__(256) void k_prep(
    const float* __restrict__ x, unsigned short* __restrict__ xb,
    const float* __restrict__ w_qkv, unsigned short* __restrict__ wqkvT,
    const float* __restrict__ w_proj, unsigned short* __restrict__ wprojT) {
  __shared__ float tile[64][65];
  int bid = blockIdx.x, tid = threadIdx.x;
  if (bid < 4096) {
    int i = bid * 256 + tid;
    float4 f = reinterpret_cast<const float4*>(x)[i];
    union { unsigned short u[4]; unsigned long long v; } o;
    o.u[0] = f2bf(f.x); o.u[1] = f2bf(f.y); o.u[2] = f2bf(f.z); o.u[3] = f2bf(f.w);
    reinterpret_cast<unsigned long long*>(xb)[i] = o.v;
    return;
  }
  const float* in; unsigned short* out; int R, C, bx, by;
  if (bid < 4864) {
    int rel = bid - 4096;
    in = w_qkv; out = wqkvT; R = 1024; C = 3072; bx = rel % 48; by = rel / 48;
  } else {
    int rel = bid - 4864;
    in = w_proj; out = wprojT; R = 1024; C = 1024; bx = rel % 16; by = rel / 16;
  }
  int tx = tid & 63, ty = tid >> 6;
  int c0 = bx * 64, r0 = by * 64;
  for (int i = ty; i < 64; i += 4)
    tile[i][tx] = in[(size_t)(r0 + i) * C + c0 + tx];
  __syncthreads();
  for (int i = ty; i < 64; i += 4)
    out[(size_t)(c0 + i) * R + r0 + tx] = f2bf(tile[tx][i]);
}

// ---------------- QKV GEMM 128x128, BK=64, fused V-transpose epilogue ----------
// Frozen at the R12/R15 anchor.
__global__ __launch_bounds__(256) void k_gemm_qkv(
    const unsigned short* __restrict__ A, const unsigned short* __restrict__ Bt,
    unsigned short* __restrict__ qk, unsigned short* __restrict__ vT, int K) {
  __shared__ unsigned short As[128][64];
  __shared__ unsigned short Bs[128][64];
  int tid = threadIdx.x;
  int w = tid >> 6, lane = tid & 63, quad = lane >> 4, l16 = lane & 15;
  int wy = w >> 1, wx = w & 1;
  int rowB = blockIdx.y * 128, colB = blockIdx.x * 128;
  int srcRow = lane >> 3;
  int srcCol = (((lane & 7) ^ (srcRow & 7)) << 3);

  floatx4 acc[4][4];
  floatx4 zero4 = {0.f, 0.f, 0.f, 0.f};
#pragma unroll
  for (int mi = 0; mi < 4; ++mi)
#pragma unroll
    for (int ni = 0; ni < 4; ++ni) acc[mi][ni] = zero4;

  for (int kt = 0; kt < K; kt += 64) {
    __syncthreads();
#pragma unroll
    for (int i = 0; i < 4; ++i) {
      int r0 = w * 32 + i * 8;
      async_cp16(&A[(size_t)(rowB + r0 + srcRow) * K + kt + srcCol], &As[r0][0]);
      async_cp16(&Bt[(size_t)(colB + r0 + srcRow) * K + kt + srcCol], &Bs[r0][0]);
    }
    __syncthreads();
#pragma unroll
    for (int kh = 0; kh < 2; ++kh) {
      short8 af[4], bf_[4];
#pragma unroll
      for (int mi = 0; mi < 4; ++mi)
        af[mi] = ld8(&As[wy * 64 + mi * 16 + l16][((kh * 4 + quad) ^ (l16 & 7)) << 3]);
#pragma unroll
      for (int ni = 0; ni < 4; ++ni)
        bf_[ni] = ld8(&Bs[wx * 64 + ni * 16 + l16][((kh * 4 + quad) ^ (l16 & 7)) << 3]);
#pragma unroll
      for (int mi = 0; mi < 4; ++mi)
#pragma unroll
        for (int ni = 0; ni < 4; ++ni)
          acc[mi][ni] = MFMA16(af[mi], bf_[ni], acc[mi][ni]);
    }
  }

  if (colB < 2048) {  // Q/K: row-major, LD 2048
#pragma unroll
    for (int mi = 0; mi < 4; ++mi) {
      int row = rowB + wy * 64 + mi * 16 + quad * 4;
#pragma unroll
      for (int ni = 0; ni < 4; ++ni) {
        int col = colB + wx * 64 + ni * 16 + l16;
#pragma unroll
        for (int r = 0; r < 4; ++r)
          qk[(size_t)(row + r) * 2048 + col] = f2bf(acc[mi][ni][r]);
      }
    }
  } else {  // V: transposed into vT[bh][d][t], packed 4x bf16 = 8B store
#pragma unroll
    for (int mi = 0; mi < 4; ++mi) {
      int row = rowB + wy * 64 + mi * 16 + quad * 4;
      int b = row >> 11, t = row & 2047;
#pragma unroll
      for (int ni = 0; ni < 4; ++ni) {
        int hd = colB - 2048 + wx * 64 + ni * 16 + l16;  // h*64+d
        union { unsigned short u[4]; unsigned long long v; } o;
#pragma unroll
        for (int r = 0; r < 4; ++r) o.u[r] = f2bf(acc[mi][ni][r]);
        *reinterpret_cast<unsigned long long*>(
            &vT[((size_t)(b * 16) * 64 + hd) * 2048 + t]) = o.v;
      }
    }
  }
}

// ---------------- proj GEMM 128x64 tiles: 512 blocks = 2/CU -------------------
__global__ __launch_bounds__(256) void k_gemm_proj(
    const unsigned short* __restrict__ A, const unsigned short* __restrict__ Bt,
    float* __restrict__ Cout, const float* __restrict__ bias, int M, int N, int K) {
  __shared__ unsigned short As[128][64];
  __shared__ unsigned short Bs[64][64];
  int tid = threadIdx.x;
  int w = tid >> 6, lane = tid & 63, quad = lane >> 4, l16 = lane & 15;
  int rowB = blockIdx.y * 128, colB = blockIdx.x * 64;
  int srcRow = lane >> 3;
  int srcCol = (((lane & 7) ^ (srcRow & 7)) << 3);

  floatx4 acc[2][4];
  floatx4 zero4 = {0.f, 0.f, 0.f, 0.f};
#pragma unroll
  for (int mi = 0; mi < 2; ++mi)
#pragma unroll
    for (int ni = 0; ni < 4; ++ni) acc[mi][ni] = zero4;

  for (int kt = 0; kt < K; kt += 64) {
    __syncthreads();
#pragma unroll
    for (int i = 0; i < 4; ++i) {
      int r0 = w * 32 + i * 8;
      async_cp16(&A[(size_t)(rowB + r0 + srcRow) * K + kt + srcCol], &As[r0][0]);
    }
#pragma unroll
    for (int i = 0; i < 2; ++i) {
      int r0 = w * 16 + i * 8;
      async_cp16(&Bt[(size_t)(colB + r0 + srcRow) * K + kt + srcCol], &Bs[r0][0]);
    }
    __syncthreads();
#pragma unroll
    for (int kh = 0; kh < 2; ++kh) {
      short8 af[2], bf_[4];
#pragma unroll
      for (int mi = 0; mi < 2; ++mi)
        af[mi] = ld8(&As[w * 32 + mi * 16 + l16][((kh * 4 + quad) ^ (l16 & 7)) << 3]);
#pragma unroll
      for (int ni = 0; ni < 4; ++ni)
        bf_[ni] = ld8(&Bs[ni * 16 + l16][((kh * 4 + quad) ^ (l16 & 7)) << 3]);
#pragma unroll
      for (int mi = 0; mi < 2; ++mi)
#pragma unroll
        for (int ni = 0; ni < 4; ++ni)
          acc[mi][ni] = MFMA16(af[mi], bf_[ni], acc[mi][ni]);
    }
  }

#pragma unroll
  for (int mi = 0; mi < 2; ++mi) {
    int row = rowB + w * 32 + mi * 16 + quad * 4;
#pragma unroll
    for (int ni = 0; ni < 4; ++ni) {
      int col = colB + ni * 16 + l16;
      float bv = bias[col];
#pragma unroll
      for (int r = 0; r < 4; ++r)
        Cout[(size_t)(row + r) * N + col] = acc[mi][ni][r] + bv;
    }
  }
}

// ---------------- flash attention, causal, fixed-offset softmax ----------------
// R24: V direct-from-global (L2) -- LDS traffic cut 42%.
// R23 post-mortem: occupancy/scheduling fixed (6 blocks/CU, ~0 conflicts),
// kernel now LDS-port-throughput-bound: ~24KB LDS moved per wave-pass ->
// 6 blk x 16 pass x 4 waves x 24KB / 85 B/cyc ~ 45us. The PV B-fragment is
// EXACTLY vT's global layout ([d][t], 16B contiguous per lane):
//   bv = ld8(&Vp[(nd*16+l16)*T + key0 + kh*32 + quad*8])
// so V skips LDS entirely (bit-identical numerics). Deletes per wave-pass:
// 2 V stage-writes + 8 Vt reads = 10KB of 24KB. Added L2 traffic ~540MB
// (~2.2 TB/s per XCD < 4.3 ceiling); XCD-affine decode keeps each XCD's
// K/V/Q set at 3MB < 4MB L2. V-load addresses depend only on key0/nd (not
// on QK results) -> issue early, hide under softmax. LDS now 16.4KB
// (Kt + Pt). VGPR watch: must stay <=85 for 24 waves/CU (6 blocks); was 56,
// predict ~70 (drop vreg prefetch, add per-nd bv pairs).
// Frozen: R23 stride-64 XOR-swizzled Kt/Pt (16B-multiple row strides --
// R22's stride-68=136B misaligned-b128 lesson), R21 chain-split decomposition
// (j<16 direct; j>=16 two half-range blocks + separate k_combine, NO fences
// -- R20's threadfence L2-invalidate storm), ORD48 LPT order, XCD-affine
// decode, S^T = K*Q^T, fixed-offset softmax p = exp2(s*c-16), l via
// ones-MFMA, RNE b64 P-pack, reg-prefetch of next K tile.
// NO launch_bounds min-waves hint (R18 lesson).
__global__ __launch_bounds__(256) void k_attn(
    const unsigned short* __restrict__ qk, const unsigned short* __restrict__ vT,
    unsigned short* __restrict__ attn_out,
    float* __restrict__ o_part, float* __restrict__ l_part) {
  const int T = 2048, LD = 2048;
  __shared__ unsigned short Kt[64][64];    // [key][d]   64-key stage, swizzled
  __shared__ unsigned short Pt[4][16][64]; // per-wave P [q][key64], swizzled

  // decode: idx&7 = XCD slot; g = idx>>3; r = bh round; o -> ORD48 chunk
  int idx = blockIdx.x;
  int g = idx >> 3;
  int r = g & 3, o = g >> 2;
  int c = ORD48[o];
  int bh = (idx & 7) * 4 + r;              // 0..31, XCD-affine
  int b = bh >> 4, h = bh & 15;
  int tid = threadIdx.x, w = tid >> 6, lane = tid & 63;
  int quad = lane >> 4, l16 = lane & 15;

  int j, h0, h1, hf = 0, pid = 0;
  if (c < 16) {          // full tile, direct write
    j = c; h0 = 0; h1 = j + 1;
  } else {               // split pair half
    int s = c - 16; j = 16 + (s >> 1); hf = s & 1;
    int nt = j + 1, hs = (nt + 1) >> 1;
    h0 = hf ? hs : 0; h1 = hf ? nt : hs;
    pid = bh * 16 + (j - 16);              // 0..511
  }
  int q0 = j * 64;

  const unsigned short* Qp = qk + (size_t)b * T * LD + h * 64;
  const unsigned short* Kp = Qp + 1024;
  const unsigned short* Vp = vT + (size_t)bh * 64 * T;

  short8 aq[2];
  {
    const unsigned short* qrow = Qp + (size_t)(q0 + w * 16 + l16) * LD + quad * 8;
    aq[0] = ld8(qrow);
    aq[1] = ld8(qrow + 32);
  }

  short8 ones8;
  {
    unsigned short oo = 0x3F80;  // bf16 1.0
#pragma unroll
    for (int i = 0; i < 8; ++i) ones8[i] = (short)oo;
  }

  const float cscale = 0.125f * 1.44269504f;
  floatx4 o_acc[4], l_acc;
  floatx4 zero4 = {0.f, 0.f, 0.f, 0.f};
  l_acc = zero4;
#pragma unroll
  for (int nd = 0; nd < 4; ++nd) o_acc[nd] = zero4;

  // K staging coords: rows skR(+32), global col gC linear, LDS col sC swizzled
  int skR = tid >> 3;
  int gC = (tid & 7) << 3;
  int sC = (((tid & 7) ^ (skR & 7)) << 3);   // (skR+32)&7 == skR&7

  // fragment-read swizzled columns (Kt, Pt: all read rows ≡ l16 mod 8)
  int kx0 = ((quad ^ (l16 & 7)) << 3);
  int kx1 = (((quad + 4) ^ (l16 & 7)) << 3);

  short8 kreg[2];
#pragma unroll
  for (int i = 0; i < 2; ++i)
    kreg[i] = ld8(&Kp[(size_t)(h0 * 64 + skR + i * 32) * LD + gC]);

  for (int half = h0; half < h1; ++half) {
    __syncthreads();
#pragma unroll
    for (int i = 0; i < 2; ++i)
      *reinterpret_cast<short8*>(&Kt[skR + i * 32][sC]) = kreg[i];
    __syncthreads();

    if (half + 1 < h1) {  // prefetch next 64-key K tile during compute
      int key0n = (half + 1) * 64;
#pragma unroll
      for (int i = 0; i < 2; ++i)
        kreg[i] = ld8(&Kp[(size_t)(key0n + skR + i * 32) * LD + gC]);
    }

    int key0 = half * 64;

    // S^T = K Q^T; C-layout: col=q=l16, row=key=kt4*16+quad*4+reg
    floatx4 st[4];
#pragma unroll
    for (int kt4 = 0; kt4 < 4; ++kt4) {
      short8 ak0 = ld8(&Kt[kt4 * 16 + l16][kx0]);
      short8 ak1 = ld8(&Kt[kt4 * 16 + l16][kx1]);
      st[kt4] = MFMA16(ak0, aq[0], zero4);
      st[kt4] = MFMA16(ak1, aq[1], st[kt4]);
    }

    if (half == j) {  // wave-uniform: mask only on diagonal tile
      int qlane = q0 + w * 16 + l16;
#pragma unroll
      for (int kt4 = 0; kt4 < 4; ++kt4)
#pragma unroll
        for (int rr = 0; rr < 4; ++rr)
          if (key0 + kt4 * 16 + quad * 4 + rr > qlane) st[kt4][rr] = -1e30f;
    }

#pragma unroll
    for (int kt4 = 0; kt4 < 4; ++kt4) {
      unsigned u[4];
#pragma unroll
      for (int rr = 0; rr < 4; ++rr) {
        float pe = __builtin_amdgcn_exp2f(fmaf(st[kt4][rr], cscale, -16.f));
        u[rr] = __float_as_uint(pe) + 0x8000u;
      }
      unsigned lo = __builtin_amdgcn_perm(u[1], u[0], 0x07060302u);
      unsigned hi = __builtin_amdgcn_perm(u[3], u[2], 0x07060302u);
      unsigned long long pv = ((unsigned long long)hi << 32) | lo;
      int pcol = (kt4 * 16 + quad * 4) ^ ((l16 & 7) << 3);  // 8B-piece swizzle
      *reinterpret_cast<unsigned long long*>(&Pt[w][l16][pcol]) = pv;
    }

    short8 pa0 = ld8(&Pt[w][l16][kx0]);
    short8 pa1 = ld8(&Pt[w][l16][kx1]);
    // PV: V B-frags straight from global (L2-resident); 16B contiguous/lane
#pragma unroll
    for (int nd = 0; nd < 4; ++nd) {
      const unsigned short* vrow = Vp + (size_t)(nd * 16 + l16) * T + key0;
      short8 bv0 = ld8(vrow + quad * 8);
      short8 bv1 = ld8(vrow + 32 + quad * 8);
      o_acc[nd] = MFMA16(pa0, bv0, o_acc[nd]);
      o_acc[nd] = MFMA16(pa1, bv1, o_acc[nd]);
    }
    l_acc = MFMA16(pa0, ones8, l_acc);
    l_acc = MFMA16(pa1, ones8, l_acc);
  }

  if (c < 16) {  // direct epilogue (full causal range in this block)
#pragma unroll
    for (int nd = 0; nd < 4; ++nd)
#pragma unroll
      for (int rr = 0; rr < 4; ++rr) {
        int q = q0 + w * 16 + quad * 4 + rr;
        int d = nd * 16 + l16;
        attn_out[(size_t)(b * T + q) * 1024 + h * 64 + d] =
            f2bf(o_acc[nd][rr] / l_acc[rr]);
      }
    return;
  }

  // ---- split path: store f32 partials for this half, then exit ----
  int slot = pid * 2 + hf;
  float* OP = o_part + (size_t)slot * 4096;   // 64q x 64d
  float* LP = l_part + (size_t)slot * 64;
#pragma unroll
  for (int nd = 0; nd < 4; ++nd)
#pragma unroll
    for (int rr = 0; rr < 4; ++rr)
      OP[(w * 16 + quad * 4 + rr) * 64 + nd * 16 + l16] = o_acc[nd][rr];
  if (l16 == 0)
#pragma unroll
    for (int rr = 0; rr < 4; ++rr)
      LP[w * 16 + quad * 4 + rr] = l_acc[rr];
}

// ---------------- combine: additive merge of split-pair partials --------------
// 512 blocks, one per split pair (bh, j-16). Stream-ordered after k_attn:
// coherence from the runtime's inter-dispatch cache maintenance, not fences.
__global__ __launch_bounds__(256) void k_combine(
    const float* __restrict__ o_part, const float* __restrict__ l_part,
    unsigned short* __restrict__ attn_out) {
  int idx = blockIdx.x;
  int bh = ((idx & 7) << 2) | ((idx >> 3) & 3);  // 0..31
  int t = idx >> 5;                              // 0..15
  int j = 16 + t;
  int b = bh >> 4, h = bh & 15;
  int pid = bh * 16 + t;
  int q0 = j * 64;
  const int T = 2048;

  const float* PA = o_part + (size_t)(pid * 2) * 4096;
  const float* PB = PA + 4096;
  const float* LA = l_part + (size_t)(pid * 2) * 64;
  const float* LB = LA + 64;
  int tid = threadIdx.x;
#pragma unroll
  for (int pass = 0; pass < 4; ++pass) {
    int q = pass * 16 + (tid >> 4);
    int d0 = (tid & 15) * 4;
    int off = q * 64 + d0;
    float4 a = *reinterpret_cast<const float4*>(&PA[off]);
    float4 cc = *reinterpret_cast<const float4*>(&PB[off]);
    float rl = 1.0f / (LA[q] + LB[q]);
    union { unsigned short u[4]; unsigned long long v; } ob;
    ob.u[0] = f2bf((a.x + cc.x) * rl);
    ob.u[1] = f2bf((a.y + cc.y) * rl);
    ob.u[2] = f2bf((a.z + cc.z) * rl);
    ob.u[3] = f2bf((a.w + cc.w) * rl);
    *reinterpret_cast<unsigned long long*>(
        &attn_out[(size_t)(b * T + q0 + q) * 1024 + h * 64 + d0]) = ob.v;
  }
}

extern "C" void kernel_launch(void* const* d_in, const int* in_sizes, int n_in,
                              void* d_out, int out_size, void* d_ws, size_t ws_size,
                              hipStream_t stream) {
  const float* x = (const float*)d_in[0];       // [2,2048,1024]
  const float* w_qkv = (const float*)d_in[1];   // [1024,3072]
  const float* w_proj = (const float*)d_in[2];  // [1024,1024]
  const float* b_proj = (const float*)d_in[3];  // [1024]
  float* out = (float*)d_out;                   // [2,2048,1024] fp32

  char* ws = (char*)d_ws;
  unsigned short* xb     = (unsigned short*)(ws);                      // 8 MB
  unsigned short* wqkvT  = (unsigned short*)(ws + (size_t)(8  << 20)); // 6 MB
  unsigned short* wprojT = (unsigned short*)(ws + (size_t)(14 << 20)); // 2 MB
  unsigned short* qkb    = (unsigned short*)(ws + (size_t)(16 << 20)); // 16 MB (Q|K, LD 2048)
  unsigned short* attnb  = (unsigned short*)(ws + (size_t)(32 << 20)); // 8 MB
  unsigned short* vTb    = (unsigned short*)(ws + (size_t)(40 << 20)); // 8 MB
  float*          o_part = (float*)(ws + (size_t)(48 << 20));          // 16 MB (1024 x 16 KB)
  float*          l_part = (float*)(ws + (size_t)(64 << 20));          // 256 KB

  k_prep<<<5120, 256, 0, stream>>>(x, xb, w_qkv, wqkvT, w_proj, wprojT);
  k_gemm_qkv<<<dim3(3072 / 128, 4096 / 128), 256, 0, stream>>>(
      xb, wqkvT, qkb, vTb, 1024);
  k_attn<<<1536, 256, 0, stream>>>(qkb, vTb, attnb, o_part, l_part);
  k_combine<<<512, 256, 0, stream>>>(o_part, l_part, attnb);
  k_gemm_proj<<<dim3(1024 / 64, 4096 / 128), 256, 0, stream>>>(
      attnb, wprojT, out, b_proj, 4096, 1024, 1024);
}

// Round 8
// 207.033 us; speedup vs baseline: 1.0188x; 1.0188x over previous
//
#include <hip/hip_runtime.h>
#include <hip/hip_bf16.h>

typedef __attribute__((ext_vector_type(8))) short short8;
typedef __attribute__((ext_vector_type(4))) float floatx4;

#define MFMA16(a, b, c) __builtin_amdgcn_mfma_f32_16x16x32_bf16((a), (b), (c), 0, 0, 0)
#define GLOBAL_AS __attribute__((address_space(1)))
#define LDS_AS __attribute__((address_space(3)))

__device__ __forceinline__ unsigned short f2bf(float x) {
  union { float f; unsigned u; } v; v.f = x;
  unsigned r = v.u + 0x7FFFu + ((v.u >> 16) & 1u);  // RNE
  return (unsigned short)(r >> 16);
}

__device__ __forceinline__ short8 ld8(const unsigned short* p) {
  return *reinterpret_cast<const short8*>(p);
}

__device__ __forceinline__ void async_cp16(const unsigned short* g, unsigned short* l) {
  __builtin_amdgcn_global_load_lds((const GLOBAL_AS void*)g, (LDS_AS void*)l, 16, 0, 0);
}

// LPT-descending chunk order. chunk c<16: full q-tile j=c (j+1 passes).
// c>=16: s=c-16, j=16+(s>>1), half hf=s&1 of a split pair (8..16 passes).
__constant__ int ORD48[48] = {
    15, 44, 46, 47,  14, 40, 42, 43, 45,  13, 36, 38, 39, 41,
    12, 32, 34, 35, 37,  11, 28, 30, 31, 33,  10, 24, 26, 27, 29,
    9, 20, 22, 23, 25,  8, 16, 18, 19, 21,  7, 17,  6, 5, 4, 3, 2, 1, 0};

// ---------------- fused prep: x convert + both weight transposes ----------------
__global__ __launch_bounds__(256) void k_prep(
    const float* __restrict__ x, unsigned short* __restrict__ xb,
    const float* __restrict__ w_qkv, unsigned short* __restrict__ wqkvT,
    const float* __restrict__ w_proj, unsigned short* __restrict__ wprojT) {
  __shared__ float tile[64][65];
  int bid = blockIdx.x, tid = threadIdx.x;
  if (bid < 4096) {
    int i = bid * 256 + tid;
    float4 f = reinterpret_cast<const float4*>(x)[i];
    union { unsigned short u[4]; unsigned long long v; } o;
    o.u[0] = f2bf(f.x); o.u[1] = f2bf(f.y); o.u[2] = f2bf(f.z); o.u[3] = f2bf(f.w);
    reinterpret_cast<unsigned long long*>(xb)[i] = o.v;
    return;
  }
  const float* in; unsigned short* out; int R, C, bx, by;
  if (bid < 4864) {
    int rel = bid - 4096;
    in = w_qkv; out = wqkvT; R = 1024; C = 3072; bx = rel % 48; by = rel / 48;
  } else {
    int rel = bid - 4864;
    in = w_proj; out = wprojT; R = 1024; C = 1024; bx = rel % 16; by = rel / 16;
  }
  int tx = tid & 63, ty = tid >> 6;
  int c0 = bx * 64, r0 = by * 64;
  for (int i = ty; i < 64; i += 4)
    tile[i][tx] = in[(size_t)(r0 + i) * C + c0 + tx];
  __syncthreads();
  for (int i = ty; i < 64; i += 4)
    out[(size_t)(c0 + i) * R + r0 + tx] = f2bf(tile[tx][i]);
}

// ---------------- QKV GEMM 128x128, BK=64, fused V-transpose epilogue ----------
// Frozen at the R12/R15 anchor.
__global__ __launch_bounds__(256) void k_gemm_qkv(
    const unsigned short* __restrict__ A, const unsigned short* __restrict__ Bt,
    unsigned short* __restrict__ qk, unsigned short* __restrict__ vT, int K) {
  __shared__ unsigned short As[128][64];
  __shared__ unsigned short Bs[128][64];
  int tid = threadIdx.x;
  int w = tid >> 6, lane = tid & 63, quad = lane >> 4, l16 = lane & 15;
  int wy = w >> 1, wx = w & 1;
  int rowB = blockIdx.y * 128, colB = blockIdx.x * 128;
  int srcRow = lane >> 3;
  int srcCol = (((lane & 7) ^ (srcRow & 7)) << 3);

  floatx4 acc[4][4];
  floatx4 zero4 = {0.f, 0.f, 0.f, 0.f};
#pragma unroll
  for (int mi = 0; mi < 4; ++mi)
#pragma unroll
    for (int ni = 0; ni < 4; ++ni) acc[mi][ni] = zero4;

  for (int kt = 0; kt < K; kt += 64) {
    __syncthreads();
#pragma unroll
    for (int i = 0; i < 4; ++i) {
      int r0 = w * 32 + i * 8;
      async_cp16(&A[(size_t)(rowB + r0 + srcRow) * K + kt + srcCol], &As[r0][0]);
      async_cp16(&Bt[(size_t)(colB + r0 + srcRow) * K + kt + srcCol], &Bs[r0][0]);
    }
    __syncthreads();
#pragma unroll
    for (int kh = 0; kh < 2; ++kh) {
      short8 af[4], bf_[4];
#pragma unroll
      for (int mi = 0; mi < 4; ++mi)
        af[mi] = ld8(&As[wy * 64 + mi * 16 + l16][((kh * 4 + quad) ^ (l16 & 7)) << 3]);
#pragma unroll
      for (int ni = 0; ni < 4; ++ni)
        bf_[ni] = ld8(&Bs[wx * 64 + ni * 16 + l16][((kh * 4 + quad) ^ (l16 & 7)) << 3]);
#pragma unroll
      for (int mi = 0; mi < 4; ++mi)
#pragma unroll
        for (int ni = 0; ni < 4; ++ni)
          acc[mi][ni] = MFMA16(af[mi], bf_[ni], acc[mi][ni]);
    }
  }

  if (colB < 2048) {  // Q/K: row-major, LD 2048
#pragma unroll
    for (int mi = 0; mi < 4; ++mi) {
      int row = rowB + wy * 64 + mi * 16 + quad * 4;
#pragma unroll
      for (int ni = 0; ni < 4; ++ni) {
        int col = colB + wx * 64 + ni * 16 + l16;
#pragma unroll
        for (int r = 0; r < 4; ++r)
          qk[(size_t)(row + r) * 2048 + col] = f2bf(acc[mi][ni][r]);
      }
    }
  } else {  // V: transposed into vT[bh][d][t], packed 4x bf16 = 8B store
#pragma unroll
    for (int mi = 0; mi < 4; ++mi) {
      int row = rowB + wy * 64 + mi * 16 + quad * 4;
      int b = row >> 11, t = row & 2047;
#pragma unroll
      for (int ni = 0; ni < 4; ++ni) {
        int hd = colB - 2048 + wx * 64 + ni * 16 + l16;  // h*64+d
        union { unsigned short u[4]; unsigned long long v; } o;
#pragma unroll
        for (int r = 0; r < 4; ++r) o.u[r] = f2bf(acc[mi][ni][r]);
        *reinterpret_cast<unsigned long long*>(
            &vT[((size_t)(b * 16) * 64 + hd) * 2048 + t]) = o.v;
      }
    }
  }
}

// ---------------- proj GEMM 128x64 tiles: 512 blocks = 2/CU -------------------
__global__ __launch_bounds__(256) void k_gemm_proj(
    const unsigned short* __restrict__ A, const unsigned short* __restrict__ Bt,
    float* __restrict__ Cout, const float* __restrict__ bias, int M, int N, int K) {
  __shared__ unsigned short As[128][64];
  __shared__ unsigned short Bs[64][64];
  int tid = threadIdx.x;
  int w = tid >> 6, lane = tid & 63, quad = lane >> 4, l16 = lane & 15;
  int rowB = blockIdx.y * 128, colB = blockIdx.x * 64;
  int srcRow = lane >> 3;
  int srcCol = (((lane & 7) ^ (srcRow & 7)) << 3);

  floatx4 acc[2][4];
  floatx4 zero4 = {0.f, 0.f, 0.f, 0.f};
#pragma unroll
  for (int mi = 0; mi < 2; ++mi)
#pragma unroll
    for (int ni = 0; ni < 4; ++ni) acc[mi][ni] = zero4;

  for (int kt = 0; kt < K; kt += 64) {
    __syncthreads();
#pragma unroll
    for (int i = 0; i < 4; ++i) {
      int r0 = w * 32 + i * 8;
      async_cp16(&A[(size_t)(rowB + r0 + srcRow) * K + kt + srcCol], &As[r0][0]);
    }
#pragma unroll
    for (int i = 0; i < 2; ++i) {
      int r0 = w * 16 + i * 8;
      async_cp16(&Bt[(size_t)(colB + r0 + srcRow) * K + kt + srcCol], &Bs[r0][0]);
    }
    __syncthreads();
#pragma unroll
    for (int kh = 0; kh < 2; ++kh) {
      short8 af[2], bf_[4];
#pragma unroll
      for (int mi = 0; mi < 2; ++mi)
        af[mi] = ld8(&As[w * 32 + mi * 16 + l16][((kh * 4 + quad) ^ (l16 & 7)) << 3]);
#pragma unroll
      for (int ni = 0; ni < 4; ++ni)
        bf_[ni] = ld8(&Bs[ni * 16 + l16][((kh * 4 + quad) ^ (l16 & 7)) << 3]);
#pragma unroll
      for (int mi = 0; mi < 2; ++mi)
#pragma unroll
        for (int ni = 0; ni < 4; ++ni)
          acc[mi][ni] = MFMA16(af[mi], bf_[ni], acc[mi][ni]);
    }
  }

#pragma unroll
  for (int mi = 0; mi < 2; ++mi) {
    int row = rowB + w * 32 + mi * 16 + quad * 4;
#pragma unroll
    for (int ni = 0; ni < 4; ++ni) {
      int col = colB + ni * 16 + l16;
      float bv = bias[col];
#pragma unroll
      for (int r = 0; r < 4; ++r)
        Cout[(size_t)(row + r) * N + col] = acc[mi][ni][r] + bv;
    }
  }
}

// ---------------- flash attention, causal, fixed-offset softmax ----------------
// R25: V from global via BATCHED EARLY register loads (fixes R24's mechanism).
// R24 post-mortem: V-direct regressed because each bv load sat at its use
// site -> compiler emitted load/wait/MFMA x8 = eight SERIAL ~300-500cyc L2
// round-trips per pass (~5.5K cyc added). FETCH barely moved (V is L2-hit);
// VGPR stayed 56 because live ranges were minimized at latency's expense.
// Fix (G7: separate issue from use): two 4-load batches in registers --
//   bvA[4] (keys +0..31) issued at pass top, covered by QK^T + softmax;
//   bvB[4] (keys +32..63) issued right after QK^T, covered by softmax + Pt
//   round-trip. PV split into independent halves: pa0 x bvA, then pa1 x bvB.
// Each batch amortizes to ONE wait. LDS stays 16 KB (Kt+Pt only) -> traffic
// 224B/lane-pass (was 384 in R23) on the port-bound resource.
// VGPR budget: ~76-84 predicted; MUST stay <=85 for 24 waves/CU (512-reg
// pool / 6 waves/SIMD). Tripwire: VGPR>85 -> 5 blocks/CU -> revert to R23.
// Frozen: R23 stride-64 XOR-swizzled Kt/Pt (16B-multiple strides -- R22
// misaligned-b128 lesson), R21 chain-split decomposition (j<16 direct; j>=16
// two half-range blocks + separate k_combine, NO fences -- R20 lesson),
// ORD48 LPT order, XCD-affine decode, S^T = K*Q^T, fixed-offset softmax
// p = exp2(s*c-16), l via ones-MFMA, RNE b64 P-pack, K reg-prefetch.
// NO launch_bounds min-waves hint (R18 lesson).
__global__ __launch_bounds__(256) void k_attn(
    const unsigned short* __restrict__ qk, const unsigned short* __restrict__ vT,
    unsigned short* __restrict__ attn_out,
    float* __restrict__ o_part, float* __restrict__ l_part) {
  const int T = 2048, LD = 2048;
  __shared__ unsigned short Kt[64][64];    // [key][d]   64-key stage, swizzled
  __shared__ unsigned short Pt[4][16][64]; // per-wave P [q][key64], swizzled

  // decode: idx&7 = XCD slot; g = idx>>3; r = bh round; o -> ORD48 chunk
  int idx = blockIdx.x;
  int g = idx >> 3;
  int r = g & 3, o = g >> 2;
  int c = ORD48[o];
  int bh = (idx & 7) * 4 + r;              // 0..31, XCD-affine
  int b = bh >> 4, h = bh & 15;
  int tid = threadIdx.x, w = tid >> 6, lane = tid & 63;
  int quad = lane >> 4, l16 = lane & 15;

  int j, h0, h1, hf = 0, pid = 0;
  if (c < 16) {          // full tile, direct write
    j = c; h0 = 0; h1 = j + 1;
  } else {               // split pair half
    int s = c - 16; j = 16 + (s >> 1); hf = s & 1;
    int nt = j + 1, hs = (nt + 1) >> 1;
    h0 = hf ? hs : 0; h1 = hf ? nt : hs;
    pid = bh * 16 + (j - 16);              // 0..511
  }
  int q0 = j * 64;

  const unsigned short* Qp = qk + (size_t)b * T * LD + h * 64;
  const unsigned short* Kp = Qp + 1024;
  const unsigned short* Vp = vT + (size_t)bh * 64 * T;

  short8 aq[2];
  {
    const unsigned short* qrow = Qp + (size_t)(q0 + w * 16 + l16) * LD + quad * 8;
    aq[0] = ld8(qrow);
    aq[1] = ld8(qrow + 32);
  }

  short8 ones8;
  {
    unsigned short oo = 0x3F80;  // bf16 1.0
#pragma unroll
    for (int i = 0; i < 8; ++i) ones8[i] = (short)oo;
  }

  const float cscale = 0.125f * 1.44269504f;
  floatx4 o_acc[4], l_acc;
  floatx4 zero4 = {0.f, 0.f, 0.f, 0.f};
  l_acc = zero4;
#pragma unroll
  for (int nd = 0; nd < 4; ++nd) o_acc[nd] = zero4;

  // K staging coords: rows skR(+32), global col gC linear, LDS col sC swizzled
  int skR = tid >> 3;
  int gC = (tid & 7) << 3;
  int sC = (((tid & 7) ^ (skR & 7)) << 3);   // (skR+32)&7 == skR&7

  // fragment-read swizzled columns (Kt, Pt: all read rows ≡ l16 mod 8)
  int kx0 = ((quad ^ (l16 & 7)) << 3);
  int kx1 = (((quad + 4) ^ (l16 & 7)) << 3);

  // per-lane V row base: row = nd*16+l16, 16B chunk at quad*8
  const unsigned short* Vl = Vp + (size_t)l16 * T + quad * 8;

  short8 kreg[2];
#pragma unroll
  for (int i = 0; i < 2; ++i)
    kreg[i] = ld8(&Kp[(size_t)(h0 * 64 + skR + i * 32) * LD + gC]);

  for (int half = h0; half < h1; ++half) {
    __syncthreads();
#pragma unroll
    for (int i = 0; i < 2; ++i)
      *reinterpret_cast<short8*>(&Kt[skR + i * 32][sC]) = kreg[i];
    __syncthreads();

    int key0 = half * 64;

    // batch A: V keys +0..31, issued NOW, consumed after softmax (~2K cyc)
    short8 bvA[4];
#pragma unroll
    for (int nd = 0; nd < 4; ++nd)
      bvA[nd] = ld8(Vl + (size_t)(nd * 16) * T + key0);

    if (half + 1 < h1) {  // prefetch next 64-key K tile during compute
      int key0n = (half + 1) * 64;
#pragma unroll
      for (int i = 0; i < 2; ++i)
        kreg[i] = ld8(&Kp[(size_t)(key0n + skR + i * 32) * LD + gC]);
    }

    // S^T = K Q^T; C-layout: col=q=l16, row=key=kt4*16+quad*4+reg
    floatx4 st[4];
#pragma unroll
    for (int kt4 = 0; kt4 < 4; ++kt4) {
      short8 ak0 = ld8(&Kt[kt4 * 16 + l16][kx0]);
      short8 ak1 = ld8(&Kt[kt4 * 16 + l16][kx1]);
      st[kt4] = MFMA16(ak0, aq[0], zero4);
      st[kt4] = MFMA16(ak1, aq[1], st[kt4]);
    }

    // batch B: V keys +32..63, issued NOW, consumed after Pt round-trip
    short8 bvB[4];
#pragma unroll
    for (int nd = 0; nd < 4; ++nd)
      bvB[nd] = ld8(Vl + (size_t)(nd * 16) * T + key0 + 32);

    if (half == j) {  // wave-uniform: mask only on diagonal tile
      int qlane = q0 + w * 16 + l16;
#pragma unroll
      for (int kt4 = 0; kt4 < 4; ++kt4)
#pragma unroll
        for (int rr = 0; rr < 4; ++rr)
          if (key0 + kt4 * 16 + quad * 4 + rr > qlane) st[kt4][rr] = -1e30f;
    }

#pragma unroll
    for (int kt4 = 0; kt4 < 4; ++kt4) {
      unsigned u[4];
#pragma unroll
      for (int rr = 0; rr < 4; ++rr) {
        float pe = __builtin_amdgcn_exp2f(fmaf(st[kt4][rr], cscale, -16.f));
        u[rr] = __float_as_uint(pe) + 0x8000u;
      }
      unsigned lo = __builtin_amdgcn_perm(u[1], u[0], 0x07060302u);
      unsigned hi = __builtin_amdgcn_perm(u[3], u[2], 0x07060302u);
      unsigned long long pv = ((unsigned long long)hi << 32) | lo;
      int pcol = (kt4 * 16 + quad * 4) ^ ((l16 & 7) << 3);  // 8B-piece swizzle
      *reinterpret_cast<unsigned long long*>(&Pt[w][l16][pcol]) = pv;
    }

    short8 pa0 = ld8(&Pt[w][l16][kx0]);
    short8 pa1 = ld8(&Pt[w][l16][kx1]);
    // PV halves are independent accumulations: pa0 x bvA, then pa1 x bvB
#pragma unroll
    for (int nd = 0; nd < 4; ++nd)
      o_acc[nd] = MFMA16(pa0, bvA[nd], o_acc[nd]);
    l_acc = MFMA16(pa0, ones8, l_acc);
#pragma unroll
    for (int nd = 0; nd < 4; ++nd)
      o_acc[nd] = MFMA16(pa1, bvB[nd], o_acc[nd]);
    l_acc = MFMA16(pa1, ones8, l_acc);
  }

  if (c < 16) {  // direct epilogue (full causal range in this block)
#pragma unroll
    for (int nd = 0; nd < 4; ++nd)
#pragma unroll
      for (int rr = 0; rr < 4; ++rr) {
        int q = q0 + w * 16 + quad * 4 + rr;
        int d = nd * 16 + l16;
        attn_out[(size_t)(b * T + q) * 1024 + h * 64 + d] =
            f2bf(o_acc[nd][rr] / l_acc[rr]);
      }
    return;
  }

  // ---- split path: store f32 partials for this half, then exit ----
  int slot = pid * 2 + hf;
  float* OP = o_part + (size_t)slot * 4096;   // 64q x 64d
  float* LP = l_part + (size_t)slot * 64;
#pragma unroll
  for (int nd = 0; nd < 4; ++nd)
#pragma unroll
    for (int rr = 0; rr < 4; ++rr)
      OP[(w * 16 + quad * 4 + rr) * 64 + nd * 16 + l16] = o_acc[nd][rr];
  if (l16 == 0)
#pragma unroll
    for (int rr = 0; rr < 4; ++rr)
      LP[w * 16 + quad * 4 + rr] = l_acc[rr];
}

// ---------------- combine: additive merge of split-pair partials --------------
// 512 blocks, one per split pair (bh, j-16). Stream-ordered after k_attn:
// coherence from the runtime's inter-dispatch cache maintenance, not fences.
__global__ __launch_bounds__(256) void k_combine(
    const float* __restrict__ o_part, const float* __restrict__ l_part,
    unsigned short* __restrict__ attn_out) {
  int idx = blockIdx.x;
  int bh = ((idx & 7) << 2) | ((idx >> 3) & 3);  // 0..31
  int t = idx >> 5;                              // 0..15
  int j = 16 + t;
  int b = bh >> 4, h = bh & 15;
  int pid = bh * 16 + t;
  int q0 = j * 64;
  const int T = 2048;

  const float* PA = o_part + (size_t)(pid * 2) * 4096;
  const float* PB = PA + 4096;
  const float* LA = l_part + (size_t)(pid * 2) * 64;
  const float* LB = LA + 64;
  int tid = threadIdx.x;
#pragma unroll
  for (int pass = 0; pass < 4; ++pass) {
    int q = pass * 16 + (tid >> 4);
    int d0 = (tid & 15) * 4;
    int off = q * 64 + d0;
    float4 a = *reinterpret_cast<const float4*>(&PA[off]);
    float4 cc = *reinterpret_cast<const float4*>(&PB[off]);
    float rl = 1.0f / (LA[q] + LB[q]);
    union { unsigned short u[4]; unsigned long long v; } ob;
    ob.u[0] = f2bf((a.x + cc.x) * rl);
    ob.u[1] = f2bf((a.y + cc.y) * rl);
    ob.u[2] = f2bf((a.z + cc.z) * rl);
    ob.u[3] = f2bf((a.w + cc.w) * rl);
    *reinterpret_cast<unsigned long long*>(
        &attn_out[(size_t)(b * T + q0 + q) * 1024 + h * 64 + d0]) = ob.v;
  }
}

extern "C" void kernel_launch(void* const* d_in, const int* in_sizes, int n_in,
                              void* d_out, int out_size, void* d_ws, size_t ws_size,
                              hipStream_t stream) {
  const float* x = (const float*)d_in[0];       // [2,2048,1024]
  const float* w_qkv = (const float*)d_in[1];   // [1024,3072]
  const float* w_proj = (const float*)d_in[2];  // [1024,1024]
  const float* b_proj = (const float*)d_in[3];  // [1024]
  float* out = (float*)d_out;                   // [2,2048,1024] fp32

  char* ws = (char*)d_ws;
  unsigned short* xb     = (unsigned short*)(ws);                      // 8 MB
  unsigned short* wqkvT  = (unsigned short*)(ws + (size_t)(8  << 20)); // 6 MB
  unsigned short* wprojT = (unsigned short*)(ws + (size_t)(14 << 20)); // 2 MB
  unsigned short* qkb    = (unsigned short*)(ws + (size_t)(16 << 20)); // 16 MB (Q|K, LD 2048)
  unsigned short* attnb  = (unsigned short*)(ws + (size_t)(32 << 20)); // 8 MB
  unsigned short* vTb    = (unsigned short*)(ws + (size_t)(40 << 20)); // 8 MB
  float*          o_part = (float*)(ws + (size_t)(48 << 20));          // 16 MB (1024 x 16 KB)
  float*          l_part = (float*)(ws + (size_t)(64 << 20));          // 256 KB

  k_prep<<<5120, 256, 0, stream>>>(x, xb, w_qkv, wqkvT, w_proj, wprojT);
  k_gemm_qkv<<<dim3(3072 / 128, 4096 / 128), 256, 0, stream>>>(
      xb, wqkvT, qkb, vTb, 1024);
  k_attn<<<1536, 256, 0, stream>>>(qkb, vTb, attnb, o_part, l_part);
  k_combine<<<512, 256, 0, stream>>>(o_part, l_part, attnb);
  k_gemm_proj<<<dim3(1024 / 64, 4096 / 128), 256, 0, stream>>>(
      attnb, wprojT, out, b_proj, 4096, 1024, 1024);
}

// Round 9
// 168.057 us; speedup vs baseline: 1.2551x; 1.2319x over previous
//
#include <hip/hip_runtime.h>
#include <hip/hip_bf16.h>

typedef __attribute__((ext_vector_type(8))) short short8;
typedef __attribute__((ext_vector_type(4))) float floatx4;

#define MFMA16(a, b, c) __builtin_amdgcn_mfma_f32_16x16x32_bf16((a), (b), (c), 0, 0, 0)
#define GLOBAL_AS __attribute__((address_space(1)))
#define LDS_AS __attribute__((address_space(3)))

__device__ __forceinline__ unsigned short f2bf(float x) {
  union { float f; unsigned u; } v; v.f = x;
  unsigned r = v.u + 0x7FFFu + ((v.u >> 16) & 1u);  // RNE
  return (unsigned short)(r >> 16);
}

__device__ __forceinline__ short8 ld8(const unsigned short* p) {
  return *reinterpret_cast<const short8*>(p);
}

__device__ __forceinline__ void async_cp16(const unsigned short* g, unsigned short* l) {
  __builtin_amdgcn_global_load_lds((const GLOBAL_AS void*)g, (LDS_AS void*)l, 16, 0, 0);
}

// LPT-descending chunk order. chunk c<16: full q-tile j=c (j+1 passes).
// c>=16: s=c-16, j=16+(s>>1), half hf=s&1 of a split pair (8..16 passes).
__constant__ int ORD48[48] = {
    15, 44, 46, 47,  14, 40, 42, 43, 45,  13, 36, 38, 39, 41,
    12, 32, 34, 35, 37,  11, 28, 30, 31, 33,  10, 24, 26, 27, 29,
    9, 20, 22, 23, 25,  8, 16, 18, 19, 21,  7, 17,  6, 5, 4, 3, 2, 1, 0};

// ---------------- fused prep: x convert + both weight transposes ----------------
__global__ __launch_bounds__(256) void k_prep(
    const float* __restrict__ x, unsigned short* __restrict__ xb,
    const float* __restrict__ w_qkv, unsigned short* __restrict__ wqkvT,
    const float* __restrict__ w_proj, unsigned short* __restrict__ wprojT) {
  __shared__ float tile[64][65];
  int bid = blockIdx.x, tid = threadIdx.x;
  if (bid < 4096) {
    int i = bid * 256 + tid;
    float4 f = reinterpret_cast<const float4*>(x)[i];
    union { unsigned short u[4]; unsigned long long v; } o;
    o.u[0] = f2bf(f.x); o.u[1] = f2bf(f.y); o.u[2] = f2bf(f.z); o.u[3] = f2bf(f.w);
    reinterpret_cast<unsigned long long*>(xb)[i] = o.v;
    return;
  }
  const float* in; unsigned short* out; int R, C, bx, by;
  if (bid < 4864) {
    int rel = bid - 4096;
    in = w_qkv; out = wqkvT; R = 1024; C = 3072; bx = rel % 48; by = rel / 48;
  } else {
    int rel = bid - 4864;
    in = w_proj; out = wprojT; R = 1024; C = 1024; bx = rel % 16; by = rel / 16;
  }
  int tx = tid & 63, ty = tid >> 6;
  int c0 = bx * 64, r0 = by * 64;
  for (int i = ty; i < 64; i += 4)
    tile[i][tx] = in[(size_t)(r0 + i) * C + c0 + tx];
  __syncthreads();
  for (int i = ty; i < 64; i += 4)
    out[(size_t)(c0 + i) * R + r0 + tx] = f2bf(tile[tx][i]);
}

// ---------------- QKV GEMM 128x128, BK=64, fused V-transpose epilogue ----------
// Frozen at the R12/R15 anchor.
__global__ __launch_bounds__(256) void k_gemm_qkv(
    const unsigned short* __restrict__ A, const unsigned short* __restrict__ Bt,
    unsigned short* __restrict__ qk, unsigned short* __restrict__ vT, int K) {
  __shared__ unsigned short As[128][64];
  __shared__ unsigned short Bs[128][64];
  int tid = threadIdx.x;
  int w = tid >> 6, lane = tid & 63, quad = lane >> 4, l16 = lane & 15;
  int wy = w >> 1, wx = w & 1;
  int rowB = blockIdx.y * 128, colB = blockIdx.x * 128;
  int srcRow = lane >> 3;
  int srcCol = (((lane & 7) ^ (srcRow & 7)) << 3);

  floatx4 acc[4][4];
  floatx4 zero4 = {0.f, 0.f, 0.f, 0.f};
#pragma unroll
  for (int mi = 0; mi < 4; ++mi)
#pragma unroll
    for (int ni = 0; ni < 4; ++ni) acc[mi][ni] = zero4;

  for (int kt = 0; kt < K; kt += 64) {
    __syncthreads();
#pragma unroll
    for (int i = 0; i < 4; ++i) {
      int r0 = w * 32 + i * 8;
      async_cp16(&A[(size_t)(rowB + r0 + srcRow) * K + kt + srcCol], &As[r0][0]);
      async_cp16(&Bt[(size_t)(colB + r0 + srcRow) * K + kt + srcCol], &Bs[r0][0]);
    }
    __syncthreads();
#pragma unroll
    for (int kh = 0; kh < 2; ++kh) {
      short8 af[4], bf_[4];
#pragma unroll
      for (int mi = 0; mi < 4; ++mi)
        af[mi] = ld8(&As[wy * 64 + mi * 16 + l16][((kh * 4 + quad) ^ (l16 & 7)) << 3]);
#pragma unroll
      for (int ni = 0; ni < 4; ++ni)
        bf_[ni] = ld8(&Bs[wx * 64 + ni * 16 + l16][((kh * 4 + quad) ^ (l16 & 7)) << 3]);
#pragma unroll
      for (int mi = 0; mi < 4; ++mi)
#pragma unroll
        for (int ni = 0; ni < 4; ++ni)
          acc[mi][ni] = MFMA16(af[mi], bf_[ni], acc[mi][ni]);
    }
  }

  if (colB < 2048) {  // Q/K: row-major, LD 2048
#pragma unroll
    for (int mi = 0; mi < 4; ++mi) {
      int row = rowB + wy * 64 + mi * 16 + quad * 4;
#pragma unroll
      for (int ni = 0; ni < 4; ++ni) {
        int col = colB + wx * 64 + ni * 16 + l16;
#pragma unroll
        for (int r = 0; r < 4; ++r)
          qk[(size_t)(row + r) * 2048 + col] = f2bf(acc[mi][ni][r]);
      }
    }
  } else {  // V: transposed into vT[bh][d][t], packed 4x bf16 = 8B store
#pragma unroll
    for (int mi = 0; mi < 4; ++mi) {
      int row = rowB + wy * 64 + mi * 16 + quad * 4;
      int b = row >> 11, t = row & 2047;
#pragma unroll
      for (int ni = 0; ni < 4; ++ni) {
        int hd = colB - 2048 + wx * 64 + ni * 16 + l16;  // h*64+d
        union { unsigned short u[4]; unsigned long long v; } o;
#pragma unroll
        for (int r = 0; r < 4; ++r) o.u[r] = f2bf(acc[mi][ni][r]);
        *reinterpret_cast<unsigned long long*>(
            &vT[((size_t)(b * 16) * 64 + hd) * 2048 + t]) = o.v;
      }
    }
  }
}

// ---------------- proj GEMM 64x64 tiles: 1024 blocks = 4/CU -------------------
// R26: was 128x64 / 512 blocks = 2 blocks/CU = 8 waves/CU -- the same
// grid-capped concurrency disease R19 found in attn. 64x64 tiles double
// residency (4 blocks/CU, 16 waves/CU); LDS 16 KB; staging 4 cp16/thread/iter;
// acc 2x2/wave. Same proven staging+swizzle structure (linear LDS dest via
// global_load_lds, pre-swizzled global col, ((kh*4+quad)^(l16&7))<<3 reads).
// B-panel re-reads double (+128 MB, L2-resident -- harmless).
__global__ __launch_bounds__(256) void k_gemm_proj(
    const unsigned short* __restrict__ A, const unsigned short* __restrict__ Bt,
    float* __restrict__ Cout, const float* __restrict__ bias, int M, int N, int K) {
  __shared__ unsigned short As[64][64];
  __shared__ unsigned short Bs[64][64];
  int tid = threadIdx.x;
  int w = tid >> 6, lane = tid & 63, quad = lane >> 4, l16 = lane & 15;
  int wy = w >> 1, wx = w & 1;
  int rowB = blockIdx.y * 64, colB = blockIdx.x * 64;
  int srcRow = lane >> 3;
  int srcCol = (((lane & 7) ^ (srcRow & 7)) << 3);

  floatx4 acc[2][2];
  floatx4 zero4 = {0.f, 0.f, 0.f, 0.f};
#pragma unroll
  for (int mi = 0; mi < 2; ++mi)
#pragma unroll
    for (int ni = 0; ni < 2; ++ni) acc[mi][ni] = zero4;

  for (int kt = 0; kt < K; kt += 64) {
    __syncthreads();
#pragma unroll
    for (int i = 0; i < 2; ++i) {
      int r0 = w * 16 + i * 8;
      async_cp16(&A[(size_t)(rowB + r0 + srcRow) * K + kt + srcCol], &As[r0][0]);
      async_cp16(&Bt[(size_t)(colB + r0 + srcRow) * K + kt + srcCol], &Bs[r0][0]);
    }
    __syncthreads();
#pragma unroll
    for (int kh = 0; kh < 2; ++kh) {
      short8 af[2], bf_[2];
#pragma unroll
      for (int mi = 0; mi < 2; ++mi)
        af[mi] = ld8(&As[wy * 32 + mi * 16 + l16][((kh * 4 + quad) ^ (l16 & 7)) << 3]);
#pragma unroll
      for (int ni = 0; ni < 2; ++ni)
        bf_[ni] = ld8(&Bs[wx * 32 + ni * 16 + l16][((kh * 4 + quad) ^ (l16 & 7)) << 3]);
#pragma unroll
      for (int mi = 0; mi < 2; ++mi)
#pragma unroll
        for (int ni = 0; ni < 2; ++ni)
          acc[mi][ni] = MFMA16(af[mi], bf_[ni], acc[mi][ni]);
    }
  }

#pragma unroll
  for (int mi = 0; mi < 2; ++mi) {
    int row = rowB + wy * 32 + mi * 16 + quad * 4;
#pragma unroll
    for (int ni = 0; ni < 2; ++ni) {
      int col = colB + wx * 32 + ni * 16 + l16;
      float bv = bias[col];
#pragma unroll
      for (int r = 0; r < 4; ++r)
        Cout[(size_t)(row + r) * N + col] = acc[mi][ni][r] + bv;
    }
  }
}

// ---------------- flash attention, causal, fixed-offset softmax ----------------
// R26: byte-for-byte revert to R23 (best verified: attn ~42us, total 169.4).
// R24/R25 falsified V-from-global twice: scattered 16-row x 64B loads are a
// TA/L1 request-rate wall (~5.5K cyc/pass regardless of load placement);
// LDS-staged V (one coalesced read + cheap ds broadcast) is structurally 2x
// better. Kept: stride-64 XOR-swizzled Kt/Vt/Pt = 24576 B, 6 blocks/CU,
// all 1536 blocks co-resident, ~0 conflicts (R23 counters). LDS ROW STRIDES
// MUST BE 16B MULTIPLES (R22 misaligned-b128 lesson). Chain-split decomposition
// + separate k_combine, NO fences (R20 threadfence L2-invalidate storm).
// ORD48 LPT order, XCD-affine decode, S^T = K*Q^T, fixed-offset softmax
// p = exp2(s*c-16), l via ones-MFMA, RNE b64 P-pack, reg-prefetch of next
// K/V tile. NO launch_bounds min-waves hint (R18 lesson).
__global__ __launch_bounds__(256) void k_attn(
    const unsigned short* __restrict__ qk, const unsigned short* __restrict__ vT,
    unsigned short* __restrict__ attn_out,
    float* __restrict__ o_part, float* __restrict__ l_part) {
  const int T = 2048, LD = 2048;
  __shared__ unsigned short Kt[64][64];    // [key][d]   64-key stage, swizzled
  __shared__ unsigned short Vt[64][64];    // [d][key]   swizzled
  __shared__ unsigned short Pt[4][16][64]; // per-wave P [q][key64], swizzled

  // decode: idx&7 = XCD slot; g = idx>>3; r = bh round; o -> ORD48 chunk
  int idx = blockIdx.x;
  int g = idx >> 3;
  int r = g & 3, o = g >> 2;
  int c = ORD48[o];
  int bh = (idx & 7) * 4 + r;              // 0..31, XCD-affine
  int b = bh >> 4, h = bh & 15;
  int tid = threadIdx.x, w = tid >> 6, lane = tid & 63;
  int quad = lane >> 4, l16 = lane & 15;

  int j, h0, h1, hf = 0, pid = 0;
  if (c < 16) {          // full tile, direct write
    j = c; h0 = 0; h1 = j + 1;
  } else {               // split pair half
    int s = c - 16; j = 16 + (s >> 1); hf = s & 1;
    int nt = j + 1, hs = (nt + 1) >> 1;
    h0 = hf ? hs : 0; h1 = hf ? nt : hs;
    pid = bh * 16 + (j - 16);              // 0..511
  }
  int q0 = j * 64;

  const unsigned short* Qp = qk + (size_t)b * T * LD + h * 64;
  const unsigned short* Kp = Qp + 1024;
  const unsigned short* Vp = vT + (size_t)bh * 64 * T;

  short8 aq[2];
  {
    const unsigned short* qrow = Qp + (size_t)(q0 + w * 16 + l16) * LD + quad * 8;
    aq[0] = ld8(qrow);
    aq[1] = ld8(qrow + 32);
  }

  short8 ones8;
  {
    unsigned short oo = 0x3F80;  // bf16 1.0
#pragma unroll
    for (int i = 0; i < 8; ++i) ones8[i] = (short)oo;
  }

  const float cscale = 0.125f * 1.44269504f;
  floatx4 o_acc[4], l_acc;
  floatx4 zero4 = {0.f, 0.f, 0.f, 0.f};
  l_acc = zero4;
#pragma unroll
  for (int nd = 0; nd < 4; ++nd) o_acc[nd] = zero4;

  // staging coords: rows skR(+32), global col gC linear, LDS col sC swizzled
  int skR = tid >> 3;
  int gC = (tid & 7) << 3;
  int sC = (((tid & 7) ^ (skR & 7)) << 3);   // (skR+32)&7 == skR&7

  // fragment-read swizzled columns (shared by Kt, Vt, Pt: all rows ≡ l16 mod 8)
  int kx0 = ((quad ^ (l16 & 7)) << 3);
  int kx1 = (((quad + 4) ^ (l16 & 7)) << 3);

  short8 kreg[2], vreg[2];
#pragma unroll
  for (int i = 0; i < 2; ++i) {
    kreg[i] = ld8(&Kp[(size_t)(h0 * 64 + skR + i * 32) * LD + gC]);
    vreg[i] = ld8(&Vp[(size_t)(skR + i * 32) * T + h0 * 64 + gC]);
  }

  for (int half = h0; half < h1; ++half) {
    __syncthreads();
#pragma unroll
    for (int i = 0; i < 2; ++i) {
      *reinterpret_cast<short8*>(&Kt[skR + i * 32][sC]) = kreg[i];
      *reinterpret_cast<short8*>(&Vt[skR + i * 32][sC]) = vreg[i];
    }
    __syncthreads();

    if (half + 1 < h1) {  // prefetch next 64-key tile during compute
      int key0n = (half + 1) * 64;
#pragma unroll
      for (int i = 0; i < 2; ++i) {
        kreg[i] = ld8(&Kp[(size_t)(key0n + skR + i * 32) * LD + gC]);
        vreg[i] = ld8(&Vp[(size_t)(skR + i * 32) * T + key0n + gC]);
      }
    }

    int key0 = half * 64;

    // S^T = K Q^T; C-layout: col=q=l16, row=key=kt4*16+quad*4+reg
    floatx4 st[4];
#pragma unroll
    for (int kt4 = 0; kt4 < 4; ++kt4) {
      short8 ak0 = ld8(&Kt[kt4 * 16 + l16][kx0]);
      short8 ak1 = ld8(&Kt[kt4 * 16 + l16][kx1]);
      st[kt4] = MFMA16(ak0, aq[0], zero4);
      st[kt4] = MFMA16(ak1, aq[1], st[kt4]);
    }

    if (half == j) {  // wave-uniform: mask only on diagonal tile
      int qlane = q0 + w * 16 + l16;
#pragma unroll
      for (int kt4 = 0; kt4 < 4; ++kt4)
#pragma unroll
        for (int rr = 0; rr < 4; ++rr)
          if (key0 + kt4 * 16 + quad * 4 + rr > qlane) st[kt4][rr] = -1e30f;
    }

#pragma unroll
    for (int kt4 = 0; kt4 < 4; ++kt4) {
      unsigned u[4];
#pragma unroll
      for (int rr = 0; rr < 4; ++rr) {
        float pe = __builtin_amdgcn_exp2f(fmaf(st[kt4][rr], cscale, -16.f));
        u[rr] = __float_as_uint(pe) + 0x8000u;
      }
      unsigned lo = __builtin_amdgcn_perm(u[1], u[0], 0x07060302u);
      unsigned hi = __builtin_amdgcn_perm(u[3], u[2], 0x07060302u);
      unsigned long long pv = ((unsigned long long)hi << 32) | lo;
      int pcol = (kt4 * 16 + quad * 4) ^ ((l16 & 7) << 3);  // 8B-piece swizzle
      *reinterpret_cast<unsigned long long*>(&Pt[w][l16][pcol]) = pv;
    }

    short8 pa0 = ld8(&Pt[w][l16][kx0]);
    short8 pa1 = ld8(&Pt[w][l16][kx1]);
#pragma unroll
    for (int nd = 0; nd < 4; ++nd) {
      short8 bv0 = ld8(&Vt[nd * 16 + l16][kx0]);
      short8 bv1 = ld8(&Vt[nd * 16 + l16][kx1]);
      o_acc[nd] = MFMA16(pa0, bv0, o_acc[nd]);
      o_acc[nd] = MFMA16(pa1, bv1, o_acc[nd]);
    }
    l_acc = MFMA16(pa0, ones8, l_acc);
    l_acc = MFMA16(pa1, ones8, l_acc);
  }

  if (c < 16) {  // direct epilogue (full causal range in this block)
#pragma unroll
    for (int nd = 0; nd < 4; ++nd)
#pragma unroll
      for (int rr = 0; rr < 4; ++rr) {
        int q = q0 + w * 16 + quad * 4 + rr;
        int d = nd * 16 + l16;
        attn_out[(size_t)(b * T + q) * 1024 + h * 64 + d] =
            f2bf(o_acc[nd][rr] / l_acc[rr]);
      }
    return;
  }

  // ---- split path: store f32 partials for this half, then exit ----
  int slot = pid * 2 + hf;
  float* OP = o_part + (size_t)slot * 4096;   // 64q x 64d
  float* LP = l_part + (size_t)slot * 64;
#pragma unroll
  for (int nd = 0; nd < 4; ++nd)
#pragma unroll
    for (int rr = 0; rr < 4; ++rr)
      OP[(w * 16 + quad * 4 + rr) * 64 + nd * 16 + l16] = o_acc[nd][rr];
  if (l16 == 0)
#pragma unroll
    for (int rr = 0; rr < 4; ++rr)
      LP[w * 16 + quad * 4 + rr] = l_acc[rr];
}

// ---------------- combine: additive merge of split-pair partials --------------
// 512 blocks, one per split pair (bh, j-16). Stream-ordered after k_attn:
// coherence from the runtime's inter-dispatch cache maintenance, not fences.
__global__ __launch_bounds__(256) void k_combine(
    const float* __restrict__ o_part, const float* __restrict__ l_part,
    unsigned short* __restrict__ attn_out) {
  int idx = blockIdx.x;
  int bh = ((idx & 7) << 2) | ((idx >> 3) & 3);  // 0..31
  int t = idx >> 5;                              // 0..15
  int j = 16 + t;
  int b = bh >> 4, h = bh & 15;
  int pid = bh * 16 + t;
  int q0 = j * 64;
  const int T = 2048;

  const float* PA = o_part + (size_t)(pid * 2) * 4096;
  const float* PB = PA + 4096;
  const float* LA = l_part + (size_t)(pid * 2) * 64;
  const float* LB = LA + 64;
  int tid = threadIdx.x;
#pragma unroll
  for (int pass = 0; pass < 4; ++pass) {
    int q = pass * 16 + (tid >> 4);
    int d0 = (tid & 15) * 4;
    int off = q * 64 + d0;
    float4 a = *reinterpret_cast<const float4*>(&PA[off]);
    float4 cc = *reinterpret_cast<const float4*>(&PB[off]);
    float rl = 1.0f / (LA[q] + LB[q]);
    union { unsigned short u[4]; unsigned long long v; } ob;
    ob.u[0] = f2bf((a.x + cc.x) * rl);
    ob.u[1] = f2bf((a.y + cc.y) * rl);
    ob.u[2] = f2bf((a.z + cc.z) * rl);
    ob.u[3] = f2bf((a.w + cc.w) * rl);
    *reinterpret_cast<unsigned long long*>(
        &attn_out[(size_t)(b * T + q0 + q) * 1024 + h * 64 + d0]) = ob.v;
  }
}

extern "C" void kernel_launch(void* const* d_in, const int* in_sizes, int n_in,
                              void* d_out, int out_size, void* d_ws, size_t ws_size,
                              hipStream_t stream) {
  const float* x = (const float*)d_in[0];       // [2,2048,1024]
  const float* w_qkv = (const float*)d_in[1];   // [1024,3072]
  const float* w_proj = (const float*)d_in[2];  // [1024,1024]
  const float* b_proj = (const float*)d_in[3];  // [1024]
  float* out = (float*)d_out;                   // [2,2048,1024] fp32

  char* ws = (char*)d_ws;
  unsigned short* xb     = (unsigned short*)(ws);                      // 8 MB
  unsigned short* wqkvT  = (unsigned short*)(ws + (size_t)(8  << 20)); // 6 MB
  unsigned short* wprojT = (unsigned short*)(ws + (size_t)(14 << 20)); // 2 MB
  unsigned short* qkb    = (unsigned short*)(ws + (size_t)(16 << 20)); // 16 MB (Q|K, LD 2048)
  unsigned short* attnb  = (unsigned short*)(ws + (size_t)(32 << 20)); // 8 MB
  unsigned short* vTb    = (unsigned short*)(ws + (size_t)(40 << 20)); // 8 MB
  float*          o_part = (float*)(ws + (size_t)(48 << 20));          // 16 MB (1024 x 16 KB)
  float*          l_part = (float*)(ws + (size_t)(64 << 20));          // 256 KB

  k_prep<<<5120, 256, 0, stream>>>(x, xb, w_qkv, wqkvT, w_proj, wprojT);
  k_gemm_qkv<<<dim3(3072 / 128, 4096 / 128), 256, 0, stream>>>(
      xb, wqkvT, qkb, vTb, 1024);
  k_attn<<<1536, 256, 0, stream>>>(qkb, vTb, attnb, o_part, l_part);
  k_combine<<<512, 256, 0, stream>>>(o_part, l_part, attnb);
  k_gemm_proj<<<dim3(1024 / 64, 4096 / 64), 256, 0, stream>>>(
      attnb, wprojT, out, b_proj, 4096, 1024, 1024);
}

// Round 10
// 166.044 us; speedup vs baseline: 1.2703x; 1.0121x over previous
//
#include <hip/hip_runtime.h>
#include <hip/hip_bf16.h>

typedef __attribute__((ext_vector_type(8))) short short8;
typedef __attribute__((ext_vector_type(4))) float floatx4;

#define MFMA16(a, b, c) __builtin_amdgcn_mfma_f32_16x16x32_bf16((a), (b), (c), 0, 0, 0)
#define GLOBAL_AS __attribute__((address_space(1)))
#define LDS_AS __attribute__((address_space(3)))

__device__ __forceinline__ unsigned short f2bf(float x) {
  union { float f; unsigned u; } v; v.f = x;
  unsigned r = v.u + 0x7FFFu + ((v.u >> 16) & 1u);  // RNE
  return (unsigned short)(r >> 16);
}

__device__ __forceinline__ short8 ld8(const unsigned short* p) {
  return *reinterpret_cast<const short8*>(p);
}

__device__ __forceinline__ void async_cp16(const unsigned short* g, unsigned short* l) {
  __builtin_amdgcn_global_load_lds((const GLOBAL_AS void*)g, (LDS_AS void*)l, 16, 0, 0);
}

// LPT-descending chunk order. chunk c<16: full q-tile j=c (j+1 passes).
// c>=16: s=c-16, j=16+(s>>1), half hf=s&1 of a split pair (8..16 passes).
__constant__ int ORD48[48] = {
    15, 44, 46, 47,  14, 40, 42, 43, 45,  13, 36, 38, 39, 41,
    12, 32, 34, 35, 37,  11, 28, 30, 31, 33,  10, 24, 26, 27, 29,
    9, 20, 22, 23, 25,  8, 16, 18, 19, 21,  7, 17,  6, 5, 4, 3, 2, 1, 0};

// ---------------- fused prep: x convert + both weight transposes ----------------
// R27: weight-transpose stores vectorized -- each lane packs 4 bf16 into one
// 8B store (was 2B scalar/lane = 128B per wave-store on 8 MB of output;
// Common-mistake #2). Load phase unchanged (coalesced 256B row reads).
__global__ __launch_bounds__(256) void k_prep(
    const float* __restrict__ x, unsigned short* __restrict__ xb,
    const float* __restrict__ w_qkv, unsigned short* __restrict__ wqkvT,
    const float* __restrict__ w_proj, unsigned short* __restrict__ wprojT) {
  __shared__ float tile[64][65];
  int bid = blockIdx.x, tid = threadIdx.x;
  if (bid < 4096) {
    int i = bid * 256 + tid;
    float4 f = reinterpret_cast<const float4*>(x)[i];
    union { unsigned short u[4]; unsigned long long v; } o;
    o.u[0] = f2bf(f.x); o.u[1] = f2bf(f.y); o.u[2] = f2bf(f.z); o.u[3] = f2bf(f.w);
    reinterpret_cast<unsigned long long*>(xb)[i] = o.v;
    return;
  }
  const float* in; unsigned short* out; int R, C, bx, by;
  if (bid < 4864) {
    int rel = bid - 4096;
    in = w_qkv; out = wqkvT; R = 1024; C = 3072; bx = rel % 48; by = rel / 48;
  } else {
    int rel = bid - 4864;
    in = w_proj; out = wprojT; R = 1024; C = 1024; bx = rel % 16; by = rel / 16;
  }
  int tx = tid & 63, ty = tid >> 6;
  int c0 = bx * 64, r0 = by * 64;
  for (int i = ty; i < 64; i += 4)
    tile[i][tx] = in[(size_t)(r0 + i) * C + c0 + tx];
  __syncthreads();
  // vectorized transposed store: out[(c0+i)*R + r0+c4+k] = tile[c4+k][i]
  int ri = tid >> 4;          // 0..15
  int c4 = (tid & 15) * 4;    // 0,4,...,60
#pragma unroll
  for (int p = 0; p < 4; ++p) {
    int i = p * 16 + ri;
    union { unsigned short u[4]; unsigned long long v; } o;
#pragma unroll
    for (int k = 0; k < 4; ++k) o.u[k] = f2bf(tile[c4 + k][i]);
    *reinterpret_cast<unsigned long long*>(&out[(size_t)(c0 + i) * R + r0 + c4]) = o.v;
  }
}

// ---------------- QKV GEMM 128x128, BK=64, fused V-transpose epilogue ----------
// Frozen at the R12/R15 anchor.
__global__ __launch_bounds__(256) void k_gemm_qkv(
    const unsigned short* __restrict__ A, const unsigned short* __restrict__ Bt,
    unsigned short* __restrict__ qk, unsigned short* __restrict__ vT, int K) {
  __shared__ unsigned short As[128][64];
  __shared__ unsigned short Bs[128][64];
  int tid = threadIdx.x;
  int w = tid >> 6, lane = tid & 63, quad = lane >> 4, l16 = lane & 15;
  int wy = w >> 1, wx = w & 1;
  int rowB = blockIdx.y * 128, colB = blockIdx.x * 128;
  int srcRow = lane >> 3;
  int srcCol = (((lane & 7) ^ (srcRow & 7)) << 3);

  floatx4 acc[4][4];
  floatx4 zero4 = {0.f, 0.f, 0.f, 0.f};
#pragma unroll
  for (int mi = 0; mi < 4; ++mi)
#pragma unroll
    for (int ni = 0; ni < 4; ++ni) acc[mi][ni] = zero4;

  for (int kt = 0; kt < K; kt += 64) {
    __syncthreads();
#pragma unroll
    for (int i = 0; i < 4; ++i) {
      int r0 = w * 32 + i * 8;
      async_cp16(&A[(size_t)(rowB + r0 + srcRow) * K + kt + srcCol], &As[r0][0]);
      async_cp16(&Bt[(size_t)(colB + r0 + srcRow) * K + kt + srcCol], &Bs[r0][0]);
    }
    __syncthreads();
#pragma unroll
    for (int kh = 0; kh < 2; ++kh) {
      short8 af[4], bf_[4];
#pragma unroll
      for (int mi = 0; mi < 4; ++mi)
        af[mi] = ld8(&As[wy * 64 + mi * 16 + l16][((kh * 4 + quad) ^ (l16 & 7)) << 3]);
#pragma unroll
      for (int ni = 0; ni < 4; ++ni)
        bf_[ni] = ld8(&Bs[wx * 64 + ni * 16 + l16][((kh * 4 + quad) ^ (l16 & 7)) << 3]);
#pragma unroll
      for (int mi = 0; mi < 4; ++mi)
#pragma unroll
        for (int ni = 0; ni < 4; ++ni)
          acc[mi][ni] = MFMA16(af[mi], bf_[ni], acc[mi][ni]);
    }
  }

  if (colB < 2048) {  // Q/K: row-major, LD 2048
#pragma unroll
    for (int mi = 0; mi < 4; ++mi) {
      int row = rowB + wy * 64 + mi * 16 + quad * 4;
#pragma unroll
      for (int ni = 0; ni < 4; ++ni) {
        int col = colB + wx * 64 + ni * 16 + l16;
#pragma unroll
        for (int r = 0; r < 4; ++r)
          qk[(size_t)(row + r) * 2048 + col] = f2bf(acc[mi][ni][r]);
      }
    }
  } else {  // V: transposed into vT[bh][d][t], packed 4x bf16 = 8B store
#pragma unroll
    for (int mi = 0; mi < 4; ++mi) {
      int row = rowB + wy * 64 + mi * 16 + quad * 4;
      int b = row >> 11, t = row & 2047;
#pragma unroll
      for (int ni = 0; ni < 4; ++ni) {
        int hd = colB - 2048 + wx * 64 + ni * 16 + l16;  // h*64+d
        union { unsigned short u[4]; unsigned long long v; } o;
#pragma unroll
        for (int r = 0; r < 4; ++r) o.u[r] = f2bf(acc[mi][ni][r]);
        *reinterpret_cast<unsigned long long*>(
            &vT[((size_t)(b * 16) * 64 + hd) * 2048 + t]) = o.v;
      }
    }
  }
}

// ---------------- proj GEMM 64x64 tiles: 1024 blocks = 4/CU -------------------
// Frozen at R26.
__global__ __launch_bounds__(256) void k_gemm_proj(
    const unsigned short* __restrict__ A, const unsigned short* __restrict__ Bt,
    float* __restrict__ Cout, const float* __restrict__ bias, int M, int N, int K) {
  __shared__ unsigned short As[64][64];
  __shared__ unsigned short Bs[64][64];
  int tid = threadIdx.x;
  int w = tid >> 6, lane = tid & 63, quad = lane >> 4, l16 = lane & 15;
  int wy = w >> 1, wx = w & 1;
  int rowB = blockIdx.y * 64, colB = blockIdx.x * 64;
  int srcRow = lane >> 3;
  int srcCol = (((lane & 7) ^ (srcRow & 7)) << 3);

  floatx4 acc[2][2];
  floatx4 zero4 = {0.f, 0.f, 0.f, 0.f};
#pragma unroll
  for (int mi = 0; mi < 2; ++mi)
#pragma unroll
    for (int ni = 0; ni < 2; ++ni) acc[mi][ni] = zero4;

  for (int kt = 0; kt < K; kt += 64) {
    __syncthreads();
#pragma unroll
    for (int i = 0; i < 2; ++i) {
      int r0 = w * 16 + i * 8;
      async_cp16(&A[(size_t)(rowB + r0 + srcRow) * K + kt + srcCol], &As[r0][0]);
      async_cp16(&Bt[(size_t)(colB + r0 + srcRow) * K + kt + srcCol], &Bs[r0][0]);
    }
    __syncthreads();
#pragma unroll
    for (int kh = 0; kh < 2; ++kh) {
      short8 af[2], bf_[2];
#pragma unroll
      for (int mi = 0; mi < 2; ++mi)
        af[mi] = ld8(&As[wy * 32 + mi * 16 + l16][((kh * 4 + quad) ^ (l16 & 7)) << 3]);
#pragma unroll
      for (int ni = 0; ni < 2; ++ni)
        bf_[ni] = ld8(&Bs[wx * 32 + ni * 16 + l16][((kh * 4 + quad) ^ (l16 & 7)) << 3]);
#pragma unroll
      for (int mi = 0; mi < 2; ++mi)
#pragma unroll
        for (int ni = 0; ni < 2; ++ni)
          acc[mi][ni] = MFMA16(af[mi], bf_[ni], acc[mi][ni]);
    }
  }

#pragma unroll
  for (int mi = 0; mi < 2; ++mi) {
    int row = rowB + wy * 32 + mi * 16 + quad * 4;
#pragma unroll
    for (int ni = 0; ni < 2; ++ni) {
      int col = colB + wx * 32 + ni * 16 + l16;
      float bv = bias[col];
#pragma unroll
      for (int r = 0; r < 4; ++r)
        Cout[(size_t)(row + r) * N + col] = acc[mi][ni][r] + bv;
    }
  }
}

// ---------------- flash attention, causal, fixed-offset softmax ----------------
// Frozen at R23/R26 (best verified). Stride-64 XOR-swizzled Kt/Vt/Pt = 24576 B,
// 6 blocks/CU, all 1536 blocks co-resident, ~0 conflicts. LDS ROW STRIDES MUST
// BE 16B MULTIPLES (R22). V stays LDS-staged (V-from-global falsified twice:
// R24/R25 -- scattered 16-row x 64B loads are a TA/L1 request-rate wall).
// Chain-split decomposition + separate k_combine, NO fences (R20). ORD48 LPT
// order, XCD-affine decode, S^T = K*Q^T, fixed-offset softmax p=exp2(s*c-16),
// l via ones-MFMA, RNE b64 P-pack, reg-prefetch of next K/V tile.
// NO launch_bounds min-waves hint (R18).
__global__ __launch_bounds__(256) void k_attn(
    const unsigned short* __restrict__ qk, const unsigned short* __restrict__ vT,
    unsigned short* __restrict__ attn_out,
    float* __restrict__ o_part, float* __restrict__ l_part) {
  const int T = 2048, LD = 2048;
  __shared__ unsigned short Kt[64][64];    // [key][d]   64-key stage, swizzled
  __shared__ unsigned short Vt[64][64];    // [d][key]   swizzled
  __shared__ unsigned short Pt[4][16][64]; // per-wave P [q][key64], swizzled

  // decode: idx&7 = XCD slot; g = idx>>3; r = bh round; o -> ORD48 chunk
  int idx = blockIdx.x;
  int g = idx >> 3;
  int r = g & 3, o = g >> 2;
  int c = ORD48[o];
  int bh = (idx & 7) * 4 + r;              // 0..31, XCD-affine
  int b = bh >> 4, h = bh & 15;
  int tid = threadIdx.x, w = tid >> 6, lane = tid & 63;
  int quad = lane >> 4, l16 = lane & 15;

  int j, h0, h1, hf = 0, pid = 0;
  if (c < 16) {          // full tile, direct write
    j = c; h0 = 0; h1 = j + 1;
  } else {               // split pair half
    int s = c - 16; j = 16 + (s >> 1); hf = s & 1;
    int nt = j + 1, hs = (nt + 1) >> 1;
    h0 = hf ? hs : 0; h1 = hf ? nt : hs;
    pid = bh * 16 + (j - 16);              // 0..511
  }
  int q0 = j * 64;

  const unsigned short* Qp = qk + (size_t)b * T * LD + h * 64;
  const unsigned short* Kp = Qp + 1024;
  const unsigned short* Vp = vT + (size_t)bh * 64 * T;

  short8 aq[2];
  {
    const unsigned short* qrow = Qp + (size_t)(q0 + w * 16 + l16) * LD + quad * 8;
    aq[0] = ld8(qrow);
    aq[1] = ld8(qrow + 32);
  }

  short8 ones8;
  {
    unsigned short oo = 0x3F80;  // bf16 1.0
#pragma unroll
    for (int i = 0; i < 8; ++i) ones8[i] = (short)oo;
  }

  const float cscale = 0.125f * 1.44269504f;
  floatx4 o_acc[4], l_acc;
  floatx4 zero4 = {0.f, 0.f, 0.f, 0.f};
  l_acc = zero4;
#pragma unroll
  for (int nd = 0; nd < 4; ++nd) o_acc[nd] = zero4;

  // staging coords: rows skR(+32), global col gC linear, LDS col sC swizzled
  int skR = tid >> 3;
  int gC = (tid & 7) << 3;
  int sC = (((tid & 7) ^ (skR & 7)) << 3);   // (skR+32)&7 == skR&7

  // fragment-read swizzled columns (shared by Kt, Vt, Pt: all rows ≡ l16 mod 8)
  int kx0 = ((quad ^ (l16 & 7)) << 3);
  int kx1 = (((quad + 4) ^ (l16 & 7)) << 3);

  short8 kreg[2], vreg[2];
#pragma unroll
  for (int i = 0; i < 2; ++i) {
    kreg[i] = ld8(&Kp[(size_t)(h0 * 64 + skR + i * 32) * LD + gC]);
    vreg[i] = ld8(&Vp[(size_t)(skR + i * 32) * T + h0 * 64 + gC]);
  }

  for (int half = h0; half < h1; ++half) {
    __syncthreads();
#pragma unroll
    for (int i = 0; i < 2; ++i) {
      *reinterpret_cast<short8*>(&Kt[skR + i * 32][sC]) = kreg[i];
      *reinterpret_cast<short8*>(&Vt[skR + i * 32][sC]) = vreg[i];
    }
    __syncthreads();

    if (half + 1 < h1) {  // prefetch next 64-key tile during compute
      int key0n = (half + 1) * 64;
#pragma unroll
      for (int i = 0; i < 2; ++i) {
        kreg[i] = ld8(&Kp[(size_t)(key0n + skR + i * 32) * LD + gC]);
        vreg[i] = ld8(&Vp[(size_t)(skR + i * 32) * T + key0n + gC]);
      }
    }

    int key0 = half * 64;

    // S^T = K Q^T; C-layout: col=q=l16, row=key=kt4*16+quad*4+reg
    floatx4 st[4];
#pragma unroll
    for (int kt4 = 0; kt4 < 4; ++kt4) {
      short8 ak0 = ld8(&Kt[kt4 * 16 + l16][kx0]);
      short8 ak1 = ld8(&Kt[kt4 * 16 + l16][kx1]);
      st[kt4] = MFMA16(ak0, aq[0], zero4);
      st[kt4] = MFMA16(ak1, aq[1], st[kt4]);
    }

    if (half == j) {  // wave-uniform: mask only on diagonal tile
      int qlane = q0 + w * 16 + l16;
#pragma unroll
      for (int kt4 = 0; kt4 < 4; ++kt4)
#pragma unroll
        for (int rr = 0; rr < 4; ++rr)
          if (key0 + kt4 * 16 + quad * 4 + rr > qlane) st[kt4][rr] = -1e30f;
    }

#pragma unroll
    for (int kt4 = 0; kt4 < 4; ++kt4) {
      unsigned u[4];
#pragma unroll
      for (int rr = 0; rr < 4; ++rr) {
        float pe = __builtin_amdgcn_exp2f(fmaf(st[kt4][rr], cscale, -16.f));
        u[rr] = __float_as_uint(pe) + 0x8000u;
      }
      unsigned lo = __builtin_amdgcn_perm(u[1], u[0], 0x07060302u);
      unsigned hi = __builtin_amdgcn_perm(u[3], u[2], 0x07060302u);
      unsigned long long pv = ((unsigned long long)hi << 32) | lo;
      int pcol = (kt4 * 16 + quad * 4) ^ ((l16 & 7) << 3);  // 8B-piece swizzle
      *reinterpret_cast<unsigned long long*>(&Pt[w][l16][pcol]) = pv;
    }

    short8 pa0 = ld8(&Pt[w][l16][kx0]);
    short8 pa1 = ld8(&Pt[w][l16][kx1]);
#pragma unroll
    for (int nd = 0; nd < 4; ++nd) {
      short8 bv0 = ld8(&Vt[nd * 16 + l16][kx0]);
      short8 bv1 = ld8(&Vt[nd * 16 + l16][kx1]);
      o_acc[nd] = MFMA16(pa0, bv0, o_acc[nd]);
      o_acc[nd] = MFMA16(pa1, bv1, o_acc[nd]);
    }
    l_acc = MFMA16(pa0, ones8, l_acc);
    l_acc = MFMA16(pa1, ones8, l_acc);
  }

  if (c < 16) {  // direct epilogue (full causal range in this block)
#pragma unroll
    for (int nd = 0; nd < 4; ++nd)
#pragma unroll
      for (int rr = 0; rr < 4; ++rr) {
        int q = q0 + w * 16 + quad * 4 + rr;
        int d = nd * 16 + l16;
        attn_out[(size_t)(b * T + q) * 1024 + h * 64 + d] =
            f2bf(o_acc[nd][rr] / l_acc[rr]);
      }
    return;
  }

  // ---- split path: store f32 partials for this half, then exit ----
  int slot = pid * 2 + hf;
  float* OP = o_part + (size_t)slot * 4096;   // 64q x 64d
  float* LP = l_part + (size_t)slot * 64;
#pragma unroll
  for (int nd = 0; nd < 4; ++nd)
#pragma unroll
    for (int rr = 0; rr < 4; ++rr)
      OP[(w * 16 + quad * 4 + rr) * 64 + nd * 16 + l16] = o_acc[nd][rr];
  if (l16 == 0)
#pragma unroll
    for (int rr = 0; rr < 4; ++rr)
      LP[w * 16 + quad * 4 + rr] = l_acc[rr];
}

// ---------------- combine: additive merge of split-pair partials --------------
// R27: 1024 blocks (2 q-passes each; was 512 x 4) -- memory-bound merge was
// 2 blocks/CU with serial dependent float4 chains. Bit 9 selects the q-half,
// so XCD affinity (idx&7) is preserved for both halves. Stream-ordered after
// k_attn: coherence from runtime inter-dispatch cache maintenance, no fences.
__global__ __launch_bounds__(256) void k_combine(
    const float* __restrict__ o_part, const float* __restrict__ l_part,
    unsigned short* __restrict__ attn_out) {
  int idx = blockIdx.x;
  int qh = (idx >> 9) & 1;                       // q-half 0/1
  int bh = ((idx & 7) << 2) | ((idx >> 3) & 3);  // 0..31
  int t = (idx >> 5) & 15;                       // 0..15
  int j = 16 + t;
  int b = bh >> 4, h = bh & 15;
  int pid = bh * 16 + t;
  int q0 = j * 64;
  const int T = 2048;

  const float* PA = o_part + (size_t)(pid * 2) * 4096;
  const float* PB = PA + 4096;
  const float* LA = l_part + (size_t)(pid * 2) * 64;
  const float* LB = LA + 64;
  int tid = threadIdx.x;
#pragma unroll
  for (int pass = 0; pass < 2; ++pass) {
    int q = (qh * 2 + pass) * 16 + (tid >> 4);
    int d0 = (tid & 15) * 4;
    int off = q * 64 + d0;
    float4 a = *reinterpret_cast<const float4*>(&PA[off]);
    float4 cc = *reinterpret_cast<const float4*>(&PB[off]);
    float rl = 1.0f / (LA[q] + LB[q]);
    union { unsigned short u[4]; unsigned long long v; } ob;
    ob.u[0] = f2bf((a.x + cc.x) * rl);
    ob.u[1] = f2bf((a.y + cc.y) * rl);
    ob.u[2] = f2bf((a.z + cc.z) * rl);
    ob.u[3] = f2bf((a.w + cc.w) * rl);
    *reinterpret_cast<unsigned long long*>(
        &attn_out[(size_t)(b * T + q0 + q) * 1024 + h * 64 + d0]) = ob.v;
  }
}

extern "C" void kernel_launch(void* const* d_in, const int* in_sizes, int n_in,
                              void* d_out, int out_size, void* d_ws, size_t ws_size,
                              hipStream_t stream) {
  const float* x = (const float*)d_in[0];       // [2,2048,1024]
  const float* w_qkv = (const float*)d_in[1];   // [1024,3072]
  const float* w_proj = (const float*)d_in[2];  // [1024,1024]
  const float* b_proj = (const float*)d_in[3];  // [1024]
  float* out = (float*)d_out;                   // [2,2048,1024] fp32

  char* ws = (char*)d_ws;
  unsigned short* xb     = (unsigned short*)(ws);                      // 8 MB
  unsigned short* wqkvT  = (unsigned short*)(ws + (size_t)(8  << 20)); // 6 MB
  unsigned short* wprojT = (unsigned short*)(ws + (size_t)(14 << 20)); // 2 MB
  unsigned short* qkb    = (unsigned short*)(ws + (size_t)(16 << 20)); // 16 MB (Q|K, LD 2048)
  unsigned short* attnb  = (unsigned short*)(ws + (size_t)(32 << 20)); // 8 MB
  unsigned short* vTb    = (unsigned short*)(ws + (size_t)(40 << 20)); // 8 MB
  float*          o_part = (float*)(ws + (size_t)(48 << 20));          // 16 MB (1024 x 16 KB)
  float*          l_part = (float*)(ws + (size_t)(64 << 20));          // 256 KB

  k_prep<<<5120, 256, 0, stream>>>(x, xb, w_qkv, wqkvT, w_proj, wprojT);
  k_gemm_qkv<<<dim3(3072 / 128, 4096 / 128), 256, 0, stream>>>(
      xb, wqkvT, qkb, vTb, 1024);
  k_attn<<<1536, 256, 0, stream>>>(qkb, vTb, attnb, o_part, l_part);
  k_combine<<<1024, 256, 0, stream>>>(o_part, l_part, attnb);
  k_gemm_proj<<<dim3(1024 / 64, 4096 / 64), 256, 0, stream>>>(
      attnb, wprojT, out, b_proj, 4096, 1024, 1024);
}